// Round 10
// baseline (112.079 us; speedup 1.0000x reference)
//
#include <hip/hip_runtime.h>
#include <hip/hip_bf16.h>

// MoE conv via bf16 MFMA implicit GEMM — 2 blocks/CU + half-tap dbuf weights.
// x: [32,64,64,64] f32  idx: [32] i32  Wc: [4,128,64,3,3] f32  bc: [4,128] f32
// out: [32,128,64,64] f32
//
// R9 post-mortem: totals pinned at 110.5-112.5 across all good structures;
// fixed harness cost dominates. One remaining identified serial cost in main:
// single-buffered weight refill = issue-DMA -> vmcnt(0) with ~zero distance,
// exposing ~300-500 cyc L2 latency 9x per block.
//
// Fix: HALF-TAP double buffer. Each 16 KB tap = two 8 KB halves (ich 0-3 /
// 4-7, contiguous in wre). wbuf[2][8 KB] -> LDS stays 67.6 KB = 2 blocks/CU,
// 16 waves/CU. 18 phases: {vmcnt(1) own-fill drained (next half in flight,
// issued ONE FULL PHASE earlier), barrier, 8 MFMA, barrier, issue fill(j+2)}.
// Counted vmcnt is exact: 1 load/thread/fill; cross-wave visibility = each
// wave drains its own fill before the open barrier (proven R2/R4 pattern).
// Everything else identical to R9 (best-tier): 512 blocks x 512 thr, bijective
// XCD swizzle, direct f32->bf16 x staging, setprio, R2 LDS-transpose reorder.

#define IC 64
#define OC 128
#define HH 64
#define WW 64

typedef short short8 __attribute__((ext_vector_type(8)));
typedef ushort ushort8 __attribute__((ext_vector_type(8)));
typedef float float16 __attribute__((ext_vector_type(16)));

typedef const __attribute__((address_space(1))) void gas_t;
typedef __attribute__((address_space(3))) void las_t;

static __device__ __forceinline__ ushort f2bf(float v) {
    __hip_bfloat16 h = __float2bfloat16(v);
    return *(ushort*)&h;
}

// ---------------- pre-kernel: reorder + convert weights (R2 version) -------
// Block = (e, oc-group of 4). Phase 1: contiguous read of 2304 floats
// (coalesced), bf16 into LDS [ocl][ic*9+tap] with row pad 576->584. Phase 2:
// 288 ushort8 chunks, 8 LDS gathers each, coalesced 16B stores.
// Layout out: [e][tap][ich8][oc128][icl8].
__global__ __launch_bounds__(256)
void reorder_w(const float* __restrict__ Wc, ushort* __restrict__ wout) {
    __shared__ ushort lw[4 * 584];          // 4672 B
    const int t   = threadIdx.x;
    const int e   = blockIdx.x >> 5;        // 0..3
    const int oc0 = (blockIdx.x & 31) * 4;  // 0,4,..,124
    const float* src = Wc + (size_t)(e * 128 + oc0) * 576;
#pragma unroll
    for (int k = 0; k < 9; ++k) {           // 9*256 = 2304 floats
        const int f   = k * 256 + t;
        const int ocl = f / 576;
        const int rem = f - ocl * 576;      // ic*9 + tap
        lw[ocl * 584 + rem] = f2bf(src[f]);
    }
    __syncthreads();
#pragma unroll
    for (int k = 0; k < 2; ++k) {
        const int n = k * 256 + t;          // 0..287 = tap(9) x ich(8) x ocl(4)
        if (n < 288) {
            const int ocl = n & 3, ich = (n >> 2) & 7, tap = n >> 5;
            ushort8 v;
#pragma unroll
            for (int icl = 0; icl < 8; ++icl)
                v[icl] = lw[ocl * 584 + (ich * 8 + icl) * 9 + tap];
            *(ushort8*)(wout +
                ((((size_t)(e * 9 + tap) * 8 + ich) * 128 + oc0 + ocl) * 8)) = v;
        }
    }
}

// ---------------- main kernel ----------------
__global__ __launch_bounds__(512, 4)
void moe_conv_mfma(const float* __restrict__ x, const int* __restrict__ idx,
                   const ushort* __restrict__ wre, const float* __restrict__ bc,
                   float* __restrict__ out) {
    __shared__ __align__(16) ushort xs[6 * 8 * 66 * 8];  // [r][ich][hc][icl] 50688 B
    __shared__ __align__(16) ushort wbuf[2][4096];       // half-tap dbuf, 2x8 KB
    __shared__ float bias[128];

    const int t = threadIdx.x;

    // T1: bijective XCD swizzle (512 = 8 x 64): XCD c owns work ids
    // [64c, 64c+64) = samples 4c..4c+3 whole (16 row-quads each).
    const int lin = blockIdx.x;                 // 0..511
    const int nw  = (lin & 7) * 64 + (lin >> 3);
    const int b   = nw >> 4;                    // sample 0..31
    const int rq  = nw & 15;                    // row quad 0..15
    const int row0 = rq * 4;
    const int e    = ((unsigned)idx[b]) & 3;    // hardened expert index

    // --- per-lane MFMA coordinates ---
    const int lane31 = t & 31;
    const int lhi    = (t >> 5) & 1;
    const int wv     = t >> 6;            // 0..7
    const int w0     = wv & 1;            // oc half
    const int pr     = wv >> 1;           // output row within quad, 0..3

    const ushort* we = wre + (size_t)e * 9 * 8192;   // e-slice: 73,728 bf16

    // --- prologue: issue half-fills f(0), f(1); they fly under x staging ---
    // half j = 8 KB = 4096 ushorts; 512 thr x 16B covers it exactly.
    __builtin_amdgcn_global_load_lds((gas_t*)(we + t * 8),
                                     (las_t*)&wbuf[0][t * 8], 16, 0, 0);
    __builtin_amdgcn_global_load_lds((gas_t*)(we + 4096 + t * 8),
                                     (las_t*)&wbuf[1][t * 8], 16, 0, 0);

    // --- halo-column zeros (hc = 0, 65) + bias stage ---
    if (t < 192) {  // r(6) x ich(8) x side(2) x q(2)
        const int r = t >> 5, rem = t & 31;
        const int ich = rem >> 2, side = (rem >> 1) & 1, q = rem & 1;
        const int hc = side ? 65 : 0;
        ushort4 z = {0, 0, 0, 0};
        *(ushort4*)&xs[(((r * 8 + ich) * 66 + hc) * 8 + q * 4)] = z;
    } else if (t < 320) {
        bias[t - 192] = bc[e * OC + (t - 192)];
    }

    // --- x staging: fp32 [ic][h][w] -> bf16 [r(6)][ich][hc][icl] ---
    const float* xb = x + (size_t)b * IC * HH * WW;
    {
        const int gc   = t & 63;          // coalesced lane = w
        const int csel = t >> 6;          // 0..7
#pragma unroll
        for (int it = 0; it < 12; ++it) {
            const int combo = it * 8 + csel;       // 0..95 = r(6) x ich(8) x q(2)
            const int r = combo >> 4, rem = combo & 15;
            const int ich = rem >> 1, q = rem & 1;
            const int gr = row0 - 1 + r;
            ushort4 u = {0, 0, 0, 0};
            if ((unsigned)gr < (unsigned)HH) {
                const int ic0 = ich * 8 + q * 4;
                u.x = f2bf(xb[((ic0 + 0) * HH + gr) * WW + gc]);
                u.y = f2bf(xb[((ic0 + 1) * HH + gr) * WW + gc]);
                u.z = f2bf(xb[((ic0 + 2) * HH + gr) * WW + gc]);
                u.w = f2bf(xb[((ic0 + 3) * HH + gr) * WW + gc]);
            }
            *(ushort4*)&xs[(((r * 8 + ich) * 66 + (gc + 1)) * 8 + q * 4)] = u;
        }
    }

    float16 acc[2][2];
#pragma unroll
    for (int a = 0; a < 2; ++a)
#pragma unroll
        for (int cg = 0; cg < 2; ++cg)
#pragma unroll
            for (int r = 0; r < 16; ++r) acc[a][cg][r] = 0.0f;

    // --- 18 half-tap phases; fill(j+1) always one full phase in flight ---
#pragma unroll
    for (int j = 0; j < 18; ++j) {
        // drain own fill(j); leave fill(j+1) flying. j==0 also drains the
        // staging/halo/bias ds_writes (lgkmcnt) before the barrier.
        if (j == 0)
            asm volatile("s_waitcnt vmcnt(1) lgkmcnt(0)" ::: "memory");
        else if (j < 17)
            asm volatile("s_waitcnt vmcnt(1)" ::: "memory");
        else
            asm volatile("s_waitcnt vmcnt(0)" ::: "memory");
        __builtin_amdgcn_s_barrier();   // all waves' fill(j) + xs visible

        const int tap = j >> 1;
        const int kh  = tap / 3;
        const int kw  = tap - kh * 3;
        const int rr  = pr + kh;             // staged row 0..5
        const int hb  = lane31 + kw;         // halo col for cg=0

        __builtin_amdgcn_s_setprio(1);
#pragma unroll
        for (int kss = 0; kss < 2; ++kss) {
            const int ich  = (j & 1) * 4 + kss * 2 + lhi;  // global ich 0..7
            const int ichl = kss * 2 + lhi;                // local within half
            const short8 a0 = *(const short8*)&wbuf[j & 1][(ichl * 128 + w0 * 64 + lane31) * 8];
            const short8 a1 = *(const short8*)&wbuf[j & 1][(ichl * 128 + w0 * 64 + 32 + lane31) * 8];
            const short8 b0 = *(const short8*)&xs[((rr * 8 + ich) * 66 + hb) * 8];
            const short8 b1 = *(const short8*)&xs[((rr * 8 + ich) * 66 + hb + 32) * 8];
            acc[0][0] = __builtin_amdgcn_mfma_f32_32x32x16_bf16(a0, b0, acc[0][0], 0, 0, 0);
            acc[0][1] = __builtin_amdgcn_mfma_f32_32x32x16_bf16(a0, b1, acc[0][1], 0, 0, 0);
            acc[1][0] = __builtin_amdgcn_mfma_f32_32x32x16_bf16(a1, b0, acc[1][0], 0, 0, 0);
            acc[1][1] = __builtin_amdgcn_mfma_f32_32x32x16_bf16(a1, b1, acc[1][1], 0, 0, 0);
        }
        __builtin_amdgcn_s_setprio(0);

        __builtin_amdgcn_s_barrier();   // all waves done reading wbuf[j&1]
        if (j < 16) {                   // refill that slot with half j+2
            __builtin_amdgcn_global_load_lds(
                (gas_t*)(we + (j + 2) * 4096 + t * 8),
                (las_t*)&wbuf[j & 1][t * 8], 16, 0, 0);
        }
    }

    // --- epilogue: C/D layout col=lane&31, row=(reg&3)+8*(reg>>2)+4*(lane>>5) ---
#pragma unroll
    for (int a = 0; a < 2; ++a) {
        const int ocb = w0 * 64 + a * 32 + 4 * lhi;
#pragma unroll
        for (int reg = 0; reg < 16; ++reg) {
            const int oc = ocb + (reg & 3) + 8 * (reg >> 2);
            const float bv = bias[oc];
            const size_t base = (((size_t)b * OC + oc) * HH + (row0 + pr)) * WW;
            out[base + lane31]      = acc[a][0][reg] + bv;
            out[base + 32 + lane31] = acc[a][1][reg] + bv;
        }
    }
}

extern "C" void kernel_launch(void* const* d_in, const int* in_sizes, int n_in,
                              void* d_out, int out_size, void* d_ws, size_t ws_size,
                              hipStream_t stream) {
    const float* x   = (const float*)d_in[0];
    const int*   idx = (const int*)d_in[1];
    const float* Wc  = (const float*)d_in[2];
    const float* bc  = (const float*)d_in[3];
    float* out  = (float*)d_out;
    ushort* wre = (ushort*)d_ws;   // 294,912 bf16 = 576 KB scratch

    reorder_w<<<128, 256, 0, stream>>>(Wc, wre);    // 128*2304 = 294,912 = |Wc|
    moe_conv_mfma<<<512, 512, 0, stream>>>(x, idx, wre, bc, out);
}

// Round 11
// 111.614 us; speedup vs baseline: 1.0042x; 1.0042x over previous
//
#include <hip/hip_runtime.h>
#include <hip/hip_bf16.h>

// MoE conv via bf16 MFMA implicit GEMM — R10 minus XCD swizzle (natural grid).
// x: [32,64,64,64] f32  idx: [32] i32  Wc: [4,128,64,3,3] f32  bc: [4,128] f32
// out: [32,128,64,64] f32
//
// Ledger (8 benches, solved jointly): fixed harness ~74 us (fill 42 + restores
// ~32); mains: R4=42 measured; R2/R6/R9/R10 ~36; R0 ~32-34 = best. R0's only
// untested delta vs R9/R10: NO XCD swizzle. Documented mechanism (m160): T1
// swizzle COSTS ~2% when working set is L3-fit — ours is (x 32 MB, Wc 1.2 MB,
// out write-only). The natural dim3(16,32) grid already gives same-sample
// adjacency for dispatch-order L2 locality.
//
// Single change this round: natural grid (bx=row-quad, by=sample), as R0.
// Kept from R10: half-tap double-buffered weight DMA (wbuf[2][8KB], counted
// vmcnt(1), fill always one full phase in flight), 512 blocks x 512 thr =
// 2 blocks/CU, 16 waves/CU (launch_bounds(512,4), 2x2 accs = 64 acc VGPRs),
// direct f32->bf16 x staging, setprio, R2 LDS-transpose reorder (~2 us).
// LDS 50688(xs) + 16384(wbuf) + 512(bias) = 67.6 KB -> 2 blocks/CU.

#define IC 64
#define OC 128
#define HH 64
#define WW 64

typedef short short8 __attribute__((ext_vector_type(8)));
typedef ushort ushort8 __attribute__((ext_vector_type(8)));
typedef float float16 __attribute__((ext_vector_type(16)));

typedef const __attribute__((address_space(1))) void gas_t;
typedef __attribute__((address_space(3))) void las_t;

static __device__ __forceinline__ ushort f2bf(float v) {
    __hip_bfloat16 h = __float2bfloat16(v);
    return *(ushort*)&h;
}

// ---------------- pre-kernel: reorder + convert weights (R2 version) -------
// Block = (e, oc-group of 4). Phase 1: contiguous read of 2304 floats
// (coalesced), bf16 into LDS [ocl][ic*9+tap] with row pad 576->584. Phase 2:
// 288 ushort8 chunks, 8 LDS gathers each, coalesced 16B stores.
// Layout out: [e][tap][ich8][oc128][icl8].
__global__ __launch_bounds__(256)
void reorder_w(const float* __restrict__ Wc, ushort* __restrict__ wout) {
    __shared__ ushort lw[4 * 584];          // 4672 B
    const int t   = threadIdx.x;
    const int e   = blockIdx.x >> 5;        // 0..3
    const int oc0 = (blockIdx.x & 31) * 4;  // 0,4,..,124
    const float* src = Wc + (size_t)(e * 128 + oc0) * 576;
#pragma unroll
    for (int k = 0; k < 9; ++k) {           // 9*256 = 2304 floats
        const int f   = k * 256 + t;
        const int ocl = f / 576;
        const int rem = f - ocl * 576;      // ic*9 + tap
        lw[ocl * 584 + rem] = f2bf(src[f]);
    }
    __syncthreads();
#pragma unroll
    for (int k = 0; k < 2; ++k) {
        const int n = k * 256 + t;          // 0..287 = tap(9) x ich(8) x ocl(4)
        if (n < 288) {
            const int ocl = n & 3, ich = (n >> 2) & 7, tap = n >> 5;
            ushort8 v;
#pragma unroll
            for (int icl = 0; icl < 8; ++icl)
                v[icl] = lw[ocl * 584 + (ich * 8 + icl) * 9 + tap];
            *(ushort8*)(wout +
                ((((size_t)(e * 9 + tap) * 8 + ich) * 128 + oc0 + ocl) * 8)) = v;
        }
    }
}

// ---------------- main kernel ----------------
__global__ __launch_bounds__(512, 4)
void moe_conv_mfma(const float* __restrict__ x, const int* __restrict__ idx,
                   const ushort* __restrict__ wre, const float* __restrict__ bc,
                   float* __restrict__ out) {
    __shared__ __align__(16) ushort xs[6 * 8 * 66 * 8];  // [r][ich][hc][icl] 50688 B
    __shared__ __align__(16) ushort wbuf[2][4096];       // half-tap dbuf, 2x8 KB
    __shared__ float bias[128];

    const int t = threadIdx.x;

    // Natural grid (R0's): bx = row quad, by = sample. No XCD swizzle —
    // everything is L3-fit, swizzle only disrupts dispatch adjacency (m160).
    const int rq   = blockIdx.x;                // row quad 0..15
    const int b    = blockIdx.y;                // sample 0..31
    const int row0 = rq * 4;
    const int e    = ((unsigned)idx[b]) & 3;    // hardened expert index

    // --- per-lane MFMA coordinates ---
    const int lane31 = t & 31;
    const int lhi    = (t >> 5) & 1;
    const int wv     = t >> 6;            // 0..7
    const int w0     = wv & 1;            // oc half
    const int pr     = wv >> 1;           // output row within quad, 0..3

    const ushort* we = wre + (size_t)e * 9 * 8192;   // e-slice: 73,728 bf16

    // --- prologue: issue half-fills f(0), f(1); they fly under x staging ---
    // half j = 8 KB = 4096 ushorts; 512 thr x 16B covers it exactly.
    __builtin_amdgcn_global_load_lds((gas_t*)(we + t * 8),
                                     (las_t*)&wbuf[0][t * 8], 16, 0, 0);
    __builtin_amdgcn_global_load_lds((gas_t*)(we + 4096 + t * 8),
                                     (las_t*)&wbuf[1][t * 8], 16, 0, 0);

    // --- halo-column zeros (hc = 0, 65) + bias stage ---
    if (t < 192) {  // r(6) x ich(8) x side(2) x q(2)
        const int r = t >> 5, rem = t & 31;
        const int ich = rem >> 2, side = (rem >> 1) & 1, q = rem & 1;
        const int hc = side ? 65 : 0;
        ushort4 z = {0, 0, 0, 0};
        *(ushort4*)&xs[(((r * 8 + ich) * 66 + hc) * 8 + q * 4)] = z;
    } else if (t < 320) {
        bias[t - 192] = bc[e * OC + (t - 192)];
    }

    // --- x staging: fp32 [ic][h][w] -> bf16 [r(6)][ich][hc][icl] ---
    const float* xb = x + (size_t)b * IC * HH * WW;
    {
        const int gc   = t & 63;          // coalesced lane = w
        const int csel = t >> 6;          // 0..7
#pragma unroll
        for (int it = 0; it < 12; ++it) {
            const int combo = it * 8 + csel;       // 0..95 = r(6) x ich(8) x q(2)
            const int r = combo >> 4, rem = combo & 15;
            const int ich = rem >> 1, q = rem & 1;
            const int gr = row0 - 1 + r;
            ushort4 u = {0, 0, 0, 0};
            if ((unsigned)gr < (unsigned)HH) {
                const int ic0 = ich * 8 + q * 4;
                u.x = f2bf(xb[((ic0 + 0) * HH + gr) * WW + gc]);
                u.y = f2bf(xb[((ic0 + 1) * HH + gr) * WW + gc]);
                u.z = f2bf(xb[((ic0 + 2) * HH + gr) * WW + gc]);
                u.w = f2bf(xb[((ic0 + 3) * HH + gr) * WW + gc]);
            }
            *(ushort4*)&xs[(((r * 8 + ich) * 66 + (gc + 1)) * 8 + q * 4)] = u;
        }
    }

    float16 acc[2][2];
#pragma unroll
    for (int a = 0; a < 2; ++a)
#pragma unroll
        for (int cg = 0; cg < 2; ++cg)
#pragma unroll
            for (int r = 0; r < 16; ++r) acc[a][cg][r] = 0.0f;

    // --- 18 half-tap phases; fill(j+1) always one full phase in flight ---
#pragma unroll
    for (int j = 0; j < 18; ++j) {
        // drain own fill(j); leave fill(j+1) flying. j==0 also drains the
        // staging/halo/bias ds_writes (lgkmcnt) before the barrier.
        if (j == 0)
            asm volatile("s_waitcnt vmcnt(1) lgkmcnt(0)" ::: "memory");
        else if (j < 17)
            asm volatile("s_waitcnt vmcnt(1)" ::: "memory");
        else
            asm volatile("s_waitcnt vmcnt(0)" ::: "memory");
        __builtin_amdgcn_s_barrier();   // all waves' fill(j) + xs visible

        const int tap = j >> 1;
        const int kh  = tap / 3;
        const int kw  = tap - kh * 3;
        const int rr  = pr + kh;             // staged row 0..5
        const int hb  = lane31 + kw;         // halo col for cg=0

        __builtin_amdgcn_s_setprio(1);
#pragma unroll
        for (int kss = 0; kss < 2; ++kss) {
            const int ich  = (j & 1) * 4 + kss * 2 + lhi;  // global ich 0..7
            const int ichl = kss * 2 + lhi;                // local within half
            const short8 a0 = *(const short8*)&wbuf[j & 1][(ichl * 128 + w0 * 64 + lane31) * 8];
            const short8 a1 = *(const short8*)&wbuf[j & 1][(ichl * 128 + w0 * 64 + 32 + lane31) * 8];
            const short8 b0 = *(const short8*)&xs[((rr * 8 + ich) * 66 + hb) * 8];
            const short8 b1 = *(const short8*)&xs[((rr * 8 + ich) * 66 + hb + 32) * 8];
            acc[0][0] = __builtin_amdgcn_mfma_f32_32x32x16_bf16(a0, b0, acc[0][0], 0, 0, 0);
            acc[0][1] = __builtin_amdgcn_mfma_f32_32x32x16_bf16(a0, b1, acc[0][1], 0, 0, 0);
            acc[1][0] = __builtin_amdgcn_mfma_f32_32x32x16_bf16(a1, b0, acc[1][0], 0, 0, 0);
            acc[1][1] = __builtin_amdgcn_mfma_f32_32x32x16_bf16(a1, b1, acc[1][1], 0, 0, 0);
        }
        __builtin_amdgcn_s_setprio(0);

        __builtin_amdgcn_s_barrier();   // all waves done reading wbuf[j&1]
        if (j < 16) {                   // refill that slot with half j+2
            __builtin_amdgcn_global_load_lds(
                (gas_t*)(we + (j + 2) * 4096 + t * 8),
                (las_t*)&wbuf[j & 1][t * 8], 16, 0, 0);
        }
    }

    // --- epilogue: C/D layout col=lane&31, row=(reg&3)+8*(reg>>2)+4*(lane>>5) ---
#pragma unroll
    for (int a = 0; a < 2; ++a) {
        const int ocb = w0 * 64 + a * 32 + 4 * lhi;
#pragma unroll
        for (int reg = 0; reg < 16; ++reg) {
            const int oc = ocb + (reg & 3) + 8 * (reg >> 2);
            const float bv = bias[oc];
            const size_t base = (((size_t)b * OC + oc) * HH + (row0 + pr)) * WW;
            out[base + lane31]      = acc[a][0][reg] + bv;
            out[base + 32 + lane31] = acc[a][1][reg] + bv;
        }
    }
}

extern "C" void kernel_launch(void* const* d_in, const int* in_sizes, int n_in,
                              void* d_out, int out_size, void* d_ws, size_t ws_size,
                              hipStream_t stream) {
    const float* x   = (const float*)d_in[0];
    const int*   idx = (const int*)d_in[1];
    const float* Wc  = (const float*)d_in[2];
    const float* bc  = (const float*)d_in[3];
    float* out  = (float*)d_out;
    ushort* wre = (ushort*)d_ws;   // 294,912 bf16 = 576 KB scratch

    reorder_w<<<128, 256, 0, stream>>>(Wc, wre);    // 128*2304 = 294,912 = |Wc|
    dim3 grid(16, 32);             // row-quads x samples, natural order (R0)
    moe_conv_mfma<<<grid, 512, 0, stream>>>(x, idx, wre, bc, out);
}